// Round 3
// baseline (270.924 us; speedup 1.0000x reference)
//
#include <hip/hip_runtime.h>
#include <math.h>

#define SEQ 8192
#define HID 4096
#define NBLK (SEQ / 4)   // 2048 blocks, 4 waves/block, 1 row per wave

// ---------------------------------------------------------------------------
// Fused matvec + softmax.
//   Phase 1 (all blocks): energies[r] = dot(eo[r,:], hidden[:]), 1 wave/row,
//     16x fully-coalesced float4 loads per lane, shfl_xor wave reduction.
//   Phase 2 (last block to finish, via device-scope atomic counter):
//     softmax over the 8192 energies, written straight to out.
// Cross-XCD visibility: __threadfence() release after stores ->
// device-scope atomicAdd -> __threadfence() acquire before reads (G16).
// No spin-waits anywhere: every block reaches the atomicAdd unconditionally,
// so the kernel cannot deadlock regardless of dispatch order.
// ---------------------------------------------------------------------------
__global__ __launch_bounds__(256) void fused_attn_kernel(
    const float* __restrict__ hidden,     // [HID]
    const float* __restrict__ eo,         // [SEQ, HID]
    float* __restrict__ out,              // [SEQ]
    float* __restrict__ energies,         // ws: [SEQ]
    unsigned int* __restrict__ counter)   // ws: 1 uint, memset to 0 per call
{
    const int tid  = threadIdx.x;
    const int lane = tid & 63;
    const int wid  = tid >> 6;
    const int row  = (int)blockIdx.x * 4 + wid;

    const float4* __restrict__ rp = (const float4*)(eo + (size_t)row * HID);
    const float4* __restrict__ hv = (const float4*)hidden;

    float acc = 0.0f;
#pragma unroll
    for (int k = 0; k < 16; ++k) {
        float4 a = rp[k * 64 + lane];
        float4 b = hv[k * 64 + lane];     // hidden: L1/L2 resident
        acc = fmaf(a.x, b.x, acc);
        acc = fmaf(a.y, b.y, acc);
        acc = fmaf(a.z, b.z, acc);
        acc = fmaf(a.w, b.w, acc);
    }
#pragma unroll
    for (int off = 32; off > 0; off >>= 1)
        acc += __shfl_xor(acc, off, 64);
    if (lane == 0) energies[row] = acc;

    // ---- publish + elect last block ----
    __threadfence();                       // release: energy stores -> device
    __syncthreads();
    __shared__ int is_last;
    if (tid == 0)
        is_last = (atomicAdd(counter, 1u) == (unsigned)(NBLK - 1));
    __syncthreads();
    if (!is_last) return;

    // ---- last block: softmax over all SEQ energies ----
    __threadfence();                       // acquire: see other blocks' stores
    __shared__ float red[8];
    const float4* __restrict__ e4 = (const float4*)energies;
    float4* __restrict__ o4 = (float4*)out;

    float4 v[8];
    float m = -INFINITY;
#pragma unroll
    for (int i = 0; i < 8; ++i) {
        v[i] = e4[i * 256 + tid];
        m = fmaxf(m, fmaxf(fmaxf(v[i].x, v[i].y), fmaxf(v[i].z, v[i].w)));
    }
#pragma unroll
    for (int off = 32; off > 0; off >>= 1)
        m = fmaxf(m, __shfl_xor(m, off, 64));
    if (lane == 0) red[wid] = m;
    __syncthreads();
    const float gmax = fmaxf(fmaxf(red[0], red[1]), fmaxf(red[2], red[3]));

    float s = 0.0f;
#pragma unroll
    for (int i = 0; i < 8; ++i) {
        v[i].x = __expf(v[i].x - gmax);
        v[i].y = __expf(v[i].y - gmax);
        v[i].z = __expf(v[i].z - gmax);
        v[i].w = __expf(v[i].w - gmax);
        s += (v[i].x + v[i].y) + (v[i].z + v[i].w);
    }
#pragma unroll
    for (int off = 32; off > 0; off >>= 1)
        s += __shfl_xor(s, off, 64);
    if (lane == 0) red[4 + wid] = s;       // distinct slots vs red[0..3]
    __syncthreads();
    const float inv = 1.0f / ((red[4] + red[5]) + (red[6] + red[7]));

#pragma unroll
    for (int i = 0; i < 8; ++i) {
        float4 w = v[i];
        w.x *= inv; w.y *= inv; w.z *= inv; w.w *= inv;
        o4[i * 256 + tid] = w;
    }
}

extern "C" void kernel_launch(void* const* d_in, const int* in_sizes, int n_in,
                              void* d_out, int out_size, void* d_ws, size_t ws_size,
                              hipStream_t stream) {
    const float* hidden = (const float*)d_in[0];   // [1, 4096] fp32
    const float* eo     = (const float*)d_in[1];   // [8192, 4096] fp32
    float* out          = (float*)d_out;           // [1, 1, 8192] fp32
    float* energies     = (float*)d_ws;
    unsigned int* counter = (unsigned int*)((char*)d_ws + SEQ * sizeof(float));

    // zero the completion counter (graph-capturable memset node; ws is
    // poisoned 0xAA once and never re-poisoned, so this must run every call)
    hipMemsetAsync(counter, 0, sizeof(unsigned int), stream);
    fused_attn_kernel<<<NBLK, 256, 0, stream>>>(hidden, eo, out, energies, counter);
}

// Round 4
// 28.013 us; speedup vs baseline: 9.6714x; 9.6714x over previous
//
#include <hip/hip_runtime.h>
#include <math.h>

#define SEQ 8192
#define HID 4096

// ---------------------------------------------------------------------------
// Kernel 1: energies[r] = dot(encoder_outputs[r, :], hidden[:])
// One 64-lane wave per row, 4 rows per 256-thread block.
// hidden is staged once per block into LDS (16 KB) so the VMEM pipe carries
// only the eo streaming loads (16x fully-coalesced float4 per lane = 1 KiB
// per instruction); hidden fragments come from LDS on the lgkm pipe.
// ---------------------------------------------------------------------------
__global__ __launch_bounds__(256) void matvec_kernel(
    const float* __restrict__ hidden,     // [HID]
    const float* __restrict__ eo,         // [SEQ, HID]
    float* __restrict__ energies)         // [SEQ]
{
    __shared__ float4 hlds[HID / 4];      // 16 KB

    const int tid  = threadIdx.x;
    const int lane = tid & 63;
    const int wid  = tid >> 6;
    const int row  = (int)blockIdx.x * 4 + wid;

    // cooperative load of hidden into LDS: 256 threads x 4 iters x 16 B
    const float4* __restrict__ hv = (const float4*)hidden;
#pragma unroll
    for (int i = 0; i < (HID / 4) / 256; ++i)
        hlds[i * 256 + tid] = hv[i * 256 + tid];
    __syncthreads();

    const float4* __restrict__ rp = (const float4*)(eo + (size_t)row * HID);

    float acc = 0.0f;
#pragma unroll
    for (int k = 0; k < 16; ++k) {
        float4 a = rp[k * 64 + lane];     // HBM/L3 streaming
        float4 b = hlds[k * 64 + lane];   // LDS, conflict-free
        acc = fmaf(a.x, b.x, acc);
        acc = fmaf(a.y, b.y, acc);
        acc = fmaf(a.z, b.z, acc);
        acc = fmaf(a.w, b.w, acc);
    }

#pragma unroll
    for (int off = 32; off > 0; off >>= 1)
        acc += __shfl_xor(acc, off, 64);
    if (lane == 0) energies[row] = acc;
}

// ---------------------------------------------------------------------------
// Kernel 2: out = softmax(energies) over SEQ elements. Single block,
// 256 threads, float4-vectorized, values held in registers between passes.
// ---------------------------------------------------------------------------
__global__ __launch_bounds__(256) void softmax_kernel(
    const float* __restrict__ energies,   // [SEQ]
    float* __restrict__ out)              // [SEQ]
{
    __shared__ float red[8];
    const int tid  = threadIdx.x;
    const int wid  = tid >> 6;
    const int lane = tid & 63;

    const float4* __restrict__ e4 = (const float4*)energies;
    float4* __restrict__ o4 = (float4*)out;

    float4 v[8];
    float m = -INFINITY;
#pragma unroll
    for (int i = 0; i < 8; ++i) {
        v[i] = e4[i * 256 + tid];
        m = fmaxf(m, fmaxf(fmaxf(v[i].x, v[i].y), fmaxf(v[i].z, v[i].w)));
    }
#pragma unroll
    for (int off = 32; off > 0; off >>= 1)
        m = fmaxf(m, __shfl_xor(m, off, 64));
    if (lane == 0) red[wid] = m;
    __syncthreads();
    const float gmax = fmaxf(fmaxf(red[0], red[1]), fmaxf(red[2], red[3]));

    float s = 0.0f;
#pragma unroll
    for (int i = 0; i < 8; ++i) {
        v[i].x = __expf(v[i].x - gmax);
        v[i].y = __expf(v[i].y - gmax);
        v[i].z = __expf(v[i].z - gmax);
        v[i].w = __expf(v[i].w - gmax);
        s += (v[i].x + v[i].y) + (v[i].z + v[i].w);
    }
#pragma unroll
    for (int off = 32; off > 0; off >>= 1)
        s += __shfl_xor(s, off, 64);
    if (lane == 0) red[4 + wid] = s;      // distinct slots vs red[0..3]
    __syncthreads();
    const float inv = 1.0f / ((red[4] + red[5]) + (red[6] + red[7]));

#pragma unroll
    for (int i = 0; i < 8; ++i) {
        float4 w = v[i];
        w.x *= inv; w.y *= inv; w.z *= inv; w.w *= inv;
        o4[i * 256 + tid] = w;
    }
}

extern "C" void kernel_launch(void* const* d_in, const int* in_sizes, int n_in,
                              void* d_out, int out_size, void* d_ws, size_t ws_size,
                              hipStream_t stream) {
    const float* hidden = (const float*)d_in[0];   // [1, 4096] fp32
    const float* eo     = (const float*)d_in[1];   // [8192, 4096] fp32
    float* out          = (float*)d_out;           // [1, 1, 8192] fp32
    float* energies     = (float*)d_ws;            // 8192 floats scratch

    matvec_kernel<<<SEQ / 4, 256, 0, stream>>>(hidden, eo, energies);
    softmax_kernel<<<1, 256, 0, stream>>>(energies, out);
}